// Round 2
// baseline (2997.973 us; speedup 1.0000x reference)
//
#include <hip/hip_runtime.h>
#include <hip/hip_bf16.h>

// Problem dims
#define BSZ 32
#define SSZ 512
#define ISZ 512
#define HSZ 512
#define PW  32          // workgroups per direction
// ws layout (bytes)
#define XB_OFF   0ull                       // [S][64 kc][32 b][8] ushort (bf16 bits) = 16 MB
#define HEX_OFF  (16ull << 20)              // [2 dir][2 buf][64 kc][32 b][8] ushort = 128 KB
#define CTR_OFF  (HEX_OFF + (128ull << 10)) // flags: [dir] stride 2048 dwords; 32 used per dir
// placement table at dword index 4096 in flags: [2 dir][32 p] = xcc+1

typedef __attribute__((ext_vector_type(8)))  short short8;
typedef __attribute__((ext_vector_type(4)))  float f32x4;
typedef __attribute__((ext_vector_type(4)))  unsigned short us4;
typedef __attribute__((ext_vector_type(4)))  int i32x4;

__device__ __forceinline__ unsigned short f2bf(float f) {
    union { float f; unsigned u; } v; v.f = f;
    unsigned r = v.u + 0x7fffu + ((v.u >> 16) & 1u);   // RNE
    return (unsigned short)(r >> 16);
}

__device__ __forceinline__ float sigf(float x) { return 1.0f / (1.0f + __expf(-x)); }
__device__ __forceinline__ float tanhfast(float x) {
    float a = fabsf(x);
    float e = __expf(-2.0f * a);
    float t = (1.0f - e) / (1.0f + e);
    return x < 0.0f ? -t : t;
}

// async global->LDS, 16B per lane (wave-uniform LDS base + lane*16)
__device__ __forceinline__ void dma16(const unsigned short* g, unsigned short* l) {
    __builtin_amdgcn_global_load_lds((const __attribute__((address_space(1))) unsigned int*)(g),
                                     (__attribute__((address_space(3))) unsigned int*)(l), 16, 0, 0);
}

// X [B][S][I] fp32 -> Xb [t][kc][b][8] bf16-bits (MFMA A-fragment friendly layout)
__global__ void k_xpose(const float* __restrict__ X, unsigned short* __restrict__ Xb) {
    int idx = blockIdx.x * 256 + threadIdx.x;     // 2^21 threads total
    int i4 = idx & 127;                           // float4 index along I
    int t  = (idx >> 7) & 511;
    int b  = idx >> 16;
    float4 v = reinterpret_cast<const float4*>(X)[idx];
    us4 o = { f2bf(v.x), f2bf(v.y), f2bf(v.z), f2bf(v.w) };
    *reinterpret_cast<us4*>(Xb + (size_t)t * 16384 + (size_t)(i4 >> 1) * 256 + b * 8 + (i4 & 1) * 4) = o;
}

__launch_bounds__(256, 1)
__global__ void k_bilstm(const float* __restrict__ Wih_f, const float* __restrict__ Whh_f,
                         const float* __restrict__ bih_f, const float* __restrict__ bhh_f,
                         const float* __restrict__ Wih_b, const float* __restrict__ Whh_b,
                         const float* __restrict__ bih_b, const float* __restrict__ bhh_b,
                         const unsigned short* __restrict__ Xb,
                         unsigned short* h_ex, unsigned* flags, float* __restrict__ out)
{
    const int tid = threadIdx.x;
    const int grp = blockIdx.x & 7;
    if (grp >= 2) return;                // 256 blocks: XCD0 = dir0, XCD1 = dir1
    const int dir  = grp;
    const int p    = blockIdx.x >> 3;    // 0..31 : owns h-cols [16p, 16p+16)
    const int wv   = tid >> 6;
    const int ln   = tid & 63;
    const int kh   = wv >> 1;            // 0: x-projection, 1: h-recurrence
    const int half = wv & 1;             // K-half this wave owns (k in [half*256, half*256+256))
    const int q    = ln >> 4;
    const int m15  = ln & 15;

    // publish my XCC_ID for runtime placement verification
    unsigned* tab = flags + 4096;
    {
        unsigned xcc;
        asm volatile("s_getreg_b32 %0, hwreg(20, 0, 32)" : "=s"(xcc));
        if (tid == 0)
            __hip_atomic_store(tab + dir * 32 + p, (xcc & 7u) + 1u,
                               __ATOMIC_RELAXED, __HIP_MEMORY_SCOPE_AGENT);
    }

    const float* Wsel = kh ? (dir ? Whh_b : Whh_f) : (dir ? Wih_b : Wih_f);
    const float* bi   = dir ? bih_b : bih_f;
    const float* bh   = dir ? bhh_b : bhh_f;

    __shared__ float gates[4][32][67];                 // 4 partial planes (wave wv)
    __shared__ float cst[32][16];
    __shared__ float outbuf[2][32][16];                // double-buffered h (fp32) for deferred out
    __shared__ float bias[64];
    __shared__ int   mode_sh;
    __shared__ __align__(16) unsigned short xstage[2][2][8192];  // [half][buf][16KB half-tile]

    // ---- weights: each wave keeps ALL 4 gate groups for its K-half ----
    short8 breg[8][4];
#pragma unroll
    for (int ks = 0; ks < 8; ++ks) {
#pragma unroll
        for (int g = 0; g < 4; ++g) {
            const float* wr = Wsel + (size_t)(g * 512 + p * 16 + m15) * 512
                                   + half * 256 + ks * 32 + q * 8;
            short8 bb;
#pragma unroll
            for (int j = 0; j < 8; ++j) bb[j] = (short)f2bf(wr[j]);
            breg[ks][g] = bb;
        }
    }

    if (tid < 64) {
        int c = tid;
        int gr = (c >> 4) * 512 + p * 16 + (c & 15);
        bias[c] = bi[gr] + bh[gr];
    }
    for (int i = tid; i < 512; i += 256) ((float*)cst)[i] = 0.0f;

    // ---- placement discovery (deadlock-free: every owner writes its slot) ----
    if (tid < 64) {
        const unsigned* tp = tab + dir * 32 + (tid & 31);
        unsigned v;
        do { v = __hip_atomic_load(tp, __ATOMIC_RELAXED, __HIP_MEMORY_SCOPE_AGENT); } while (v == 0u);
        unsigned ref = __shfl(v, 0);
        int same = (__ballot(v == ref) == ~0ull) ? 1 : 0;
        if (tid == 0) mode_sh = same;
    }
    __syncthreads();
    const int fast = mode_sh;

    unsigned* flg = flags + (size_t)dir * 2048;
    unsigned short* hexd = h_ex + (size_t)dir * 2 * 16384;

    // ---- x prologue: async-prefetch first tile into buf 0 ----
    if (kh == 0) {
        int t0 = dir ? 511 : 0;
        const unsigned short* src = Xb + (size_t)t0 * 16384 + half * 8192 + ln * 8;
        unsigned short* lb = &xstage[half][0][0];
#pragma unroll
        for (int j = 0; j < 16; ++j) dma16(src + j * 512, lb + j * 512);
    }

    int agent_poll = 0;

    for (int s = 0; s < 512; ++s) {
        f32x4 acc[4][2];
#pragma unroll
        for (int g = 0; g < 4; ++g) { acc[g][0] = {0.f,0.f,0.f,0.f}; acc[g][1] = {0.f,0.f,0.f,0.f}; }

        if (kh == 0) {
            // ---- x-projection from LDS stage (prefetched last step) ----
            asm volatile("s_waitcnt vmcnt(0)" ::: "memory");   // DMA for this buf complete
            __builtin_amdgcn_sched_barrier(0);
            const unsigned short* xs = &xstage[half][s & 1][0];
#pragma unroll
            for (int ks = 0; ks < 8; ++ks) {
                const unsigned short* ap = xs + (ks * 4 + q) * 256 + m15 * 8;
                short8 a0 = *reinterpret_cast<const short8*>(ap);
                short8 a1 = *reinterpret_cast<const short8*>(ap + 128);
#pragma unroll
                for (int g = 0; g < 4; ++g) {
                    acc[g][0] = __builtin_amdgcn_mfma_f32_16x16x32_bf16(a0, breg[ks][g], acc[g][0], 0, 0, 0);
                    acc[g][1] = __builtin_amdgcn_mfma_f32_16x16x32_bf16(a1, breg[ks][g], acc[g][1], 0, 0, 0);
                }
            }
            // ---- deferred out store for step s-1 (x-waves have slack) ----
            if (s > 0) {
                int pt = dir ? (512 - s) : (s - 1);
                int L = half * 64 + ln; int b = L >> 2; int qd = L & 3;
                f32x4 hvv = *reinterpret_cast<const f32x4*>(&outbuf[(s - 1) & 1][b][qd * 4]);
                *reinterpret_cast<f32x4*>(&out[(size_t)b * 524288 + (size_t)pt * 1024
                                               + dir * 512 + p * 16 + qd * 4]) = hvv;
            }
        } else if (fast) {
            // ---- h-recurrence, XCD-local L2 path ----
            if (s > 0) {
                const unsigned* fp = flg + (ln & 31);
                if (!agent_poll) {
                    int spins = 0;
                    for (;;) {
                        unsigned v;
                        asm volatile("global_load_dword %0, %1, off sc0\n\t"
                                     "s_waitcnt vmcnt(0)"
                                     : "=&v"(v) : "v"(fp) : "memory");
                        if (__ballot((int)(v >= (unsigned)s)) == ~0ull) break;
                        if (++spins > 20000) { agent_poll = 1; break; }
                    }
                }
                if (agent_poll) {
                    for (;;) {
                        unsigned v = __hip_atomic_load(fp, __ATOMIC_RELAXED, __HIP_MEMORY_SCOPE_AGENT);
                        if (__ballot((int)(v >= (unsigned)s)) == ~0ull) break;
                    }
                }
                asm volatile("" ::: "memory");
            }
            const unsigned short* ab = hexd + (size_t)((s + 1) & 1) * 16384 + half * 8192;
            i32x4 A0[8], A1[8];
#pragma unroll
            for (int ks = 0; ks < 8; ++ks) {
                const unsigned short* ap = ab + (ks * 4 + q) * 256 + m15 * 8;
                asm volatile("global_load_dwordx4 %0, %2, off sc0\n\t"
                             "global_load_dwordx4 %1, %3, off sc0"
                             : "=&v"(A0[ks]), "=&v"(A1[ks])
                             : "v"(ap), "v"(ap + 128) : "memory");
            }
#pragma unroll
            for (int ks = 0; ks < 8; ++ks) {
                asm volatile("s_waitcnt vmcnt(%0)" :: "n"(14 - 2 * ks) : "memory");
                __builtin_amdgcn_sched_barrier(0);
                short8 a0 = __builtin_bit_cast(short8, A0[ks]);
                short8 a1 = __builtin_bit_cast(short8, A1[ks]);
#pragma unroll
                for (int g = 0; g < 4; ++g) {
                    acc[g][0] = __builtin_amdgcn_mfma_f32_16x16x32_bf16(a0, breg[ks][g], acc[g][0], 0, 0, 0);
                    acc[g][1] = __builtin_amdgcn_mfma_f32_16x16x32_bf16(a1, breg[ks][g], acc[g][1], 0, 0, 0);
                }
            }
        } else {
            // ---- h-recurrence, fallback agent/LLC path ----
            if (s > 0) {
                const unsigned* fp = flg + (ln & 31);
                for (;;) {
                    unsigned v = __hip_atomic_load(fp, __ATOMIC_RELAXED, __HIP_MEMORY_SCOPE_AGENT);
                    if (__ballot((int)(v >= (unsigned)s)) == ~0ull) break;
                }
                asm volatile("" ::: "memory");
            }
            const unsigned* abase = reinterpret_cast<const unsigned*>(hexd + (size_t)((s + 1) & 1) * 16384);
#pragma unroll
            for (int ks = 0; ks < 8; ++ks) {
                const unsigned* ap = abase + ((half * 32 + ks * 4 + q) * 256 + m15 * 8) / 2;
                union { short8 s8; unsigned u[4]; } ua0, ua1;
#pragma unroll
                for (int w = 0; w < 4; ++w) {
                    ua0.u[w] = __hip_atomic_load(ap + w,      __ATOMIC_RELAXED, __HIP_MEMORY_SCOPE_AGENT);
                    ua1.u[w] = __hip_atomic_load(ap + 64 + w, __ATOMIC_RELAXED, __HIP_MEMORY_SCOPE_AGENT);
                }
#pragma unroll
                for (int g = 0; g < 4; ++g) {
                    acc[g][0] = __builtin_amdgcn_mfma_f32_16x16x32_bf16(ua0.s8, breg[ks][g], acc[g][0], 0, 0, 0);
                    acc[g][1] = __builtin_amdgcn_mfma_f32_16x16x32_bf16(ua1.s8, breg[ks][g], acc[g][1], 0, 0, 0);
                }
            }
        }

        // ---- dump partial gates (plane = wv); C/D: col = ln&15, row = q*4 + r ----
#pragma unroll
        for (int g = 0; g < 4; ++g)
#pragma unroll
            for (int r = 0; r < 4; ++r) {
                gates[wv][q * 4 + r][g * 16 + m15]      = acc[g][0][r];
                gates[wv][16 + q * 4 + r][g * 16 + m15] = acc[g][1][r];
            }
        asm volatile("s_waitcnt lgkmcnt(0)" ::: "memory");
        __builtin_amdgcn_s_barrier();    // sync#1 (LDS only; x DMA stays in flight)

        // ---- gate math: all threads, (b, j0) and (b, j0+1) ----
        {
            int b  = tid >> 3;
            int j0 = (tid & 7) * 2;
            float hv01[2];
#pragma unroll
            for (int u = 0; u < 2; ++u) {
                int j = j0 + u;
                float ig = gates[0][b][j]      + gates[1][b][j]      + gates[2][b][j]      + gates[3][b][j]      + bias[j];
                float fg = gates[0][b][16 + j] + gates[1][b][16 + j] + gates[2][b][16 + j] + gates[3][b][16 + j] + bias[16 + j];
                float gg = gates[0][b][32 + j] + gates[1][b][32 + j] + gates[2][b][32 + j] + gates[3][b][32 + j] + bias[32 + j];
                float og = gates[0][b][48 + j] + gates[1][b][48 + j] + gates[2][b][48 + j] + gates[3][b][48 + j] + bias[48 + j];
                float cn = sigf(fg) * cst[b][j] + sigf(ig) * tanhfast(gg);
                cst[b][j] = cn;
                hv01[u] = sigf(og) * tanhfast(cn);
            }
            *reinterpret_cast<float2*>(&outbuf[s & 1][b][j0]) = make_float2(hv01[0], hv01[1]);
            // packed 2xbf16 h store for the next step
            int hc0 = p * 16 + j0;
            unsigned pk = (unsigned)f2bf(hv01[0]) | ((unsigned)f2bf(hv01[1]) << 16);
            unsigned* dst = reinterpret_cast<unsigned*>(
                hexd + (size_t)(s & 1) * 16384 + (size_t)(hc0 >> 3) * 256 + b * 8 + (hc0 & 7));
            if (fast) {
                asm volatile("global_store_dword %0, %1, off sc0" :: "v"(dst), "v"(pk) : "memory");
            } else {
                __hip_atomic_store(dst, pk, __ATOMIC_RELAXED, __HIP_MEMORY_SCOPE_AGENT);
            }
        }

        // ---- x-waves: issue async prefetch of next tile (rides across barriers) ----
        if (kh == 0 && s < 511) {
            int tn = dir ? (510 - s) : (s + 1);
            const unsigned short* src = Xb + (size_t)tn * 16384 + half * 8192 + ln * 8;
            unsigned short* lb = &xstage[half][(s + 1) & 1][0];
#pragma unroll
            for (int j = 0; j < 16; ++j) dma16(src + j * 512, lb + j * 512);
        }

        // ---- publish: drain h (and deferred-out) but NOT the prefetch DMA ----
        if (kh == 0) {
            if (s < 511) { asm volatile("s_waitcnt vmcnt(16)" ::: "memory"); }  // retires out+h, leaves 16 DMA
            else         { asm volatile("s_waitcnt vmcnt(0)"  ::: "memory"); }
        } else {
            asm volatile("s_waitcnt vmcnt(0)" ::: "memory");    // h-store only (loads already waited)
        }
        asm volatile("s_waitcnt lgkmcnt(0)" ::: "memory");
        __builtin_amdgcn_s_barrier();    // sync#2
        if (tid == 0) {
            if (fast) {
                unsigned sv = (unsigned)(s + 1);
                asm volatile("global_store_dword %0, %1, off sc0" :: "v"(flg + p), "v"(sv) : "memory");
            } else {
                __hip_atomic_store(flg + p, (unsigned)(s + 1), __ATOMIC_RELAXED, __HIP_MEMORY_SCOPE_AGENT);
            }
        }
    }

    // ---- epilogue: last step's out + final states (x-waves, 128 lanes) ----
    if (kh == 0) {
        int L = half * 64 + ln; int b = L >> 2; int qd = L & 3;
        int tl = dir ? 0 : 511;
        f32x4 hvv = *reinterpret_cast<const f32x4*>(&outbuf[1][b][qd * 4]);
        *reinterpret_cast<f32x4*>(&out[(size_t)b * 524288 + (size_t)tl * 1024
                                       + dir * 512 + p * 16 + qd * 4]) = hvv;
        *reinterpret_cast<f32x4*>(&out[16777216 + dir * 16384 + b * 512 + p * 16 + qd * 4]) = hvv;
        f32x4 cvv = *reinterpret_cast<const f32x4*>(&cst[b][qd * 4]);
        *reinterpret_cast<f32x4*>(&out[16777216 + 32768 + dir * 16384 + b * 512 + p * 16 + qd * 4]) = cvv;
    }
}

extern "C" void kernel_launch(void* const* d_in, const int* in_sizes, int n_in,
                              void* d_out, int out_size, void* d_ws, size_t ws_size,
                              hipStream_t stream) {
    const float* X     = (const float*)d_in[0];
    const float* Wih_f = (const float*)d_in[1];
    const float* Whh_f = (const float*)d_in[2];
    const float* bih_f = (const float*)d_in[3];
    const float* bhh_f = (const float*)d_in[4];
    const float* Wih_b = (const float*)d_in[5];
    const float* Whh_b = (const float*)d_in[6];
    const float* bih_b = (const float*)d_in[7];
    const float* bhh_b = (const float*)d_in[8];
    float* out = (float*)d_out;

    unsigned short* Xb   = (unsigned short*)((char*)d_ws + XB_OFF);
    unsigned short* h_ex = (unsigned short*)((char*)d_ws + HEX_OFF);
    unsigned*       flg  = (unsigned*)((char*)d_ws + CTR_OFF);

    // zero h_ex (h_{-1}=0) + flags + placement table
    hipMemsetAsync((char*)d_ws + HEX_OFF, 0, (128ull + 64ull) << 10, stream);
    k_xpose<<<8192, 256, 0, stream>>>(X, Xb);
    // 256 blocks (1/CU): round-robin puts (blockIdx&7)==d on XCD d.
    k_bilstm<<<256, 256, 0, stream>>>(Wih_f, Whh_f, bih_f, bhh_f,
                                      Wih_b, Whh_b, bih_b, bhh_b,
                                      Xb, h_ex, flg, out);
}